// Round 4
// baseline (1128.968 us; speedup 1.0000x reference)
//
#include <hip/hip_runtime.h>
#include <hip/hip_bf16.h>

#define I_SZ 834
#define H_SZ 190
#define F_SZ 250
#define O_SZ 512
#define T_SZ 256
#define K_SZ 1024   // I+H
#define NW   47500  // F*H: Wupd flat IS W3[1024][47500] row-major

typedef __attribute__((ext_vector_type(8))) short short8;
typedef __attribute__((ext_vector_type(4))) float f32x4;

__device__ __forceinline__ short f2bf(float f) {
    union { __hip_bfloat16 h; short s; } u;
    u.h = __float2bfloat16(f);
    return u.s;
}

// -------- K1: P[t][h] = Wrnn[h, H:]·x[t] + brnn[h] --------------------------
__global__ void __launch_bounds__(256) k1_xproj(const float* __restrict__ x,
                                                const float* __restrict__ Wrnn,
                                                const float* __restrict__ brnn,
                                                float* __restrict__ P) {
    __shared__ float xs[I_SZ];
    int t = blockIdx.x;
    for (int i = threadIdx.x; i < I_SZ; i += 256) xs[i] = x[t * I_SZ + i];
    __syncthreads();
    int wave = threadIdx.x >> 6, lane = threadIdx.x & 63;
    for (int h = wave; h < H_SZ; h += 4) {
        const float* wr = Wrnn + h * K_SZ + H_SZ;
        float s = 0.f;
        for (int i = lane; i < I_SZ; i += 64) s += wr[i] * xs[i];
        #pragma unroll
        for (int off = 32; off; off >>= 1) s += __shfl_xor(s, off, 64);
        if (lane == 0) P[t * H_SZ + h] = s + brnn[h];
    }
}

// -------- K2: sequential scan via MFMA; Whh^T in register B-fragments -------
// 2 waves. Wave w owns output cols n = w*96 .. w*96+95 (6 n-tiles of 16).
// B[kt][nt]: lane l: n = w*96+nt*16+(l&15), k = kt*32+(l>>4)*8+e  (bf16).
// A per step: row0 = h (bf16 from LDS), rows 1..15 = 0.
__global__ void __launch_bounds__(128, 1) k2_scan(const float* __restrict__ Wrnn,
                                                  const float* __restrict__ h0,
                                                  const float* __restrict__ P,
                                                  float* __restrict__ h_all,
                                                  float* __restrict__ S,
                                                  short* __restrict__ Abf) {
    __shared__ __align__(16) short hlds[192];
    const int tid = threadIdx.x;
    const int w = tid >> 6, l = tid & 63;
    const int l15 = l & 15, lg = l >> 4;
    const short8 zs = {0, 0, 0, 0, 0, 0, 0, 0};

    // one-time: preload Whh^T fragments into registers
    short8 B[6][6];
    #pragma unroll
    for (int kt = 0; kt < 6; ++kt) {
        #pragma unroll
        for (int nt = 0; nt < 6; ++nt) {
            const int n = w * 96 + nt * 16 + l15;
            short8 bf = zs;
            #pragma unroll
            for (int e = 0; e < 8; ++e) {
                const int kk = kt * 32 + lg * 8 + e;
                float v = (n < H_SZ && kk < H_SZ) ? Wrnn[n * K_SZ + kk] : 0.f;
                bf[e] = f2bf(v);
            }
            B[kt][nt] = bf;
        }
    }
    // init ALL 192 slots with 128 threads (round-3 bug: tid<192 covered only 128)
    for (int i = tid; i < 192; i += 128) {
        float v = (i < H_SZ) ? h0[i] : 0.f;
        hlds[i] = f2bf(v);
    }
    float Srun[6];
    #pragma unroll
    for (int nt = 0; nt < 6; ++nt) Srun[nt] = 0.f;
    __syncthreads();

    // prefetch P for t=0
    float pc[6];
    #pragma unroll
    for (int nt = 0; nt < 6; ++nt) {
        const int n = w * 96 + nt * 16 + l15;
        pc[nt] = (l < 16 && n < H_SZ) ? P[n] : 0.f;
    }

    for (int t = 0; t < T_SZ; ++t) {
        // a-frags: broadcast h, mask rows != 0
        short8 a[6];
        #pragma unroll
        for (int kt = 0; kt < 6; ++kt) {
            short8 ar = *reinterpret_cast<const short8*>(&hlds[kt * 32 + lg * 8]);
            a[kt] = (l15 == 0) ? ar : zs;
        }
        // prefetch P for t+1 (hides L2/L3 latency under the MFMA block)
        float pn[6];
        #pragma unroll
        for (int nt = 0; nt < 6; ++nt) {
            const int n = w * 96 + nt * 16 + l15;
            pn[nt] = (t + 1 < T_SZ && l < 16 && n < H_SZ) ? P[(t + 1) * H_SZ + n] : 0.f;
        }
        f32x4 acc[6];
        #pragma unroll
        for (int nt = 0; nt < 6; ++nt) {
            f32x4 c = {0.f, 0.f, 0.f, 0.f};
            #pragma unroll
            for (int kt = 0; kt < 6; ++kt)
                c = __builtin_amdgcn_mfma_f32_16x16x32_bf16(a[kt], B[kt][nt], c, 0, 0, 0);
            acc[nt] = c;
        }
        __syncthreads();             // all waves done reading hlds for step t
        if (l < 16) {
            #pragma unroll
            for (int nt = 0; nt < 6; ++nt) {
                const int n = w * 96 + nt * 16 + l15;
                if (n < H_SZ) {
                    float v = tanhf(acc[nt][0] + pc[nt]);
                    S[t * H_SZ + n] = Srun[nt];
                    h_all[t * H_SZ + n] = v;
                    Abf[t * K_SZ + I_SZ + n] = f2bf(v);
                    hlds[n] = f2bf(v);
                    Srun[nt] += v;
                }
            }
        }
        __syncthreads();             // h_{t+1} visible before next reads
        #pragma unroll
        for (int nt = 0; nt < 6; ++nt) pc[nt] = pn[nt];
    }
}

// -------- K2b: x-part of Abf (h-part written by k2) -------------------------
__global__ void __launch_bounds__(256) k2b_buildAx(const float* __restrict__ x,
                                                   short* __restrict__ Abf) {
    int t = blockIdx.x;
    for (int i = threadIdx.x; i < I_SZ; i += 256)
        Abf[t * K_SZ + i] = f2bf(x[t * I_SZ + i]);
}

// -------- K3: transposed MFMA GEMM C^T[n][t] = W3^T @ A^T, fused S-contract -
// Block: 64 n-rows (bn0..bn0+63), all 256 t. 8 waves = 4(n-tile) x 2(t-half).
// Wave tile: 16 n x 128 t (8 t-tiles). h lives on the REGISTER axis ->
// epilogue S-contraction is in-register + 2 shfl + atomicAdd.
__global__ void __launch_bounds__(512, 1) k3_mfma(const float* __restrict__ Wupd,
                                                  const short* __restrict__ Abf,
                                                  const float* __restrict__ S,
                                                  float* __restrict__ zprime) {
    __shared__ __align__(16) float Bs[2][32][66];   // fp32 W-slab [k=32][n=64 pad 66]
    const int tid = threadIdx.x;
    const int bn0 = blockIdx.x * 64;
    const int l = tid & 63, wv = tid >> 6;
    const int wn = wv & 3;              // n-tile 0..3
    const int wt = wv >> 2;             // t-half 0..1
    const int l15 = l & 15, lg = l >> 4;

    // staging: thread -> (k-row sr, 4 cols at sc)
    const int sr = tid >> 4;
    const int sc = (tid & 15) * 4;
    const bool sval = (bn0 + sc + 4) <= NW;     // NW % 4 == 0
    const float* wsrc = Wupd + (size_t)sr * NW + bn0 + sc;

    float4 f = sval ? *reinterpret_cast<const float4*>(wsrc)
                    : make_float4(0.f, 0.f, 0.f, 0.f);

    f32x4 acc[8];
    #pragma unroll
    for (int tt = 0; tt < 8; ++tt) acc[tt] = (f32x4){0.f, 0.f, 0.f, 0.f};

    // prologue: write slab 0
    *reinterpret_cast<float2*>(&Bs[0][sr][sc])     = make_float2(f.x, f.y);
    *reinterpret_cast<float2*>(&Bs[0][sr][sc + 2]) = make_float2(f.z, f.w);
    __syncthreads();

    for (int ks = 0; ks < 32; ++ks) {
        const int cur = ks & 1;
        if (ks < 31) {                  // prefetch next slab (hidden under MFMA)
            const float* nsrc = wsrc + (size_t)(ks + 1) * 32 * NW;
            f = sval ? *reinterpret_cast<const float4*>(nsrc)
                     : make_float4(0.f, 0.f, 0.f, 0.f);
        }
        // B-operand: activations, col = t (lane l15), k = lg*8+e -> b128
        short8 bfr[8];
        #pragma unroll
        for (int tt = 0; tt < 8; ++tt) {
            const short* ap = Abf + (size_t)(wt * 128 + tt * 16 + l15) * K_SZ + ks * 32 + lg * 8;
            bfr[tt] = *reinterpret_cast<const short8*>(ap);
        }
        // A-operand: W3^T, row = n (lane l15), k = lg*8+e  (fp32 LDS -> bf16)
        short8 afr;
        #pragma unroll
        for (int e = 0; e < 8; ++e)
            afr[e] = f2bf(Bs[cur][lg * 8 + e][wn * 16 + l15]);
        #pragma unroll
        for (int tt = 0; tt < 8; ++tt)
            acc[tt] = __builtin_amdgcn_mfma_f32_16x16x32_bf16(afr, bfr[tt], acc[tt], 0, 0, 0);

        if (ks < 31) {
            *reinterpret_cast<float2*>(&Bs[cur ^ 1][sr][sc])     = make_float2(f.x, f.y);
            *reinterpret_cast<float2*>(&Bs[cur ^ 1][sr][sc + 2]) = make_float2(f.z, f.w);
            __syncthreads();            // single barrier per iter suffices
        }
    }

    // epilogue: z'[t][j] += sum_h C^T[n][t] * S[t][h(n)], bucketed by j
    const int jlo = bn0 / H_SZ;
    float pj[8][2];
    #pragma unroll
    for (int tt = 0; tt < 8; ++tt) { pj[tt][0] = 0.f; pj[tt][1] = 0.f; }
    #pragma unroll
    for (int r = 0; r < 4; ++r) {
        const int n = bn0 + wn * 16 + lg * 4 + r;
        const bool ok = n < NW;
        const int nc = ok ? n : NW - 1;
        const int j = nc / H_SZ;
        const int h = nc - j * H_SZ;
        const bool b0 = (j == jlo);
        #pragma unroll
        for (int tt = 0; tt < 8; ++tt) {
            const int t = wt * 128 + tt * 16 + l15;
            const float sv = S[t * H_SZ + h];
            const float prod = ok ? acc[tt][r] * sv : 0.f;
            pj[tt][0] += b0 ? prod : 0.f;
            pj[tt][1] += b0 ? 0.f : prod;
        }
    }
    #pragma unroll
    for (int tt = 0; tt < 8; ++tt) {
        #pragma unroll
        for (int b = 0; b < 2; ++b) {
            float v = pj[tt][b];
            v += __shfl_xor(v, 16, 64);
            v += __shfl_xor(v, 32, 64);
            if (lg == 0) {
                const int j = jlo + b;
                if (j < F_SZ) {
                    const int t = wt * 128 + tt * 16 + l15;
                    atomicAdd(&zprime[t * F_SZ + j], v);
                }
            }
        }
    }
}

// -------- K4: z -> selu -> @W2 + b2 -----------------------------------------
__global__ void __launch_bounds__(256) k4_out(const float* __restrict__ x,
                                              const float* __restrict__ h_all,
                                              const float* __restrict__ W1,
                                              const float* __restrict__ bupd,
                                              const float* __restrict__ b1,
                                              const float* __restrict__ W2,
                                              const float* __restrict__ b2,
                                              const float* __restrict__ zprime,
                                              float* __restrict__ out) {
    __shared__ float as[K_SZ];
    __shared__ float ys[256];
    int t = blockIdx.x;
    int tid = threadIdx.x;
    for (int i = tid; i < K_SZ; i += 256)
        as[i] = (i < I_SZ) ? x[t * I_SZ + i] : h_all[t * H_SZ + (i - I_SZ)];
    __syncthreads();
    if (tid < F_SZ) {
        float d1 = 0.f, d2 = 0.f;
        #pragma unroll 4
        for (int i = 0; i < K_SZ; ++i) {
            float av = as[i];
            d1 += av * W1[i * F_SZ + tid];
            d2 += av * bupd[i * F_SZ + tid];
        }
        float z = zprime[t * F_SZ + tid] + d1 + (float)t * d2 + b1[tid];
        const float scale = 1.0507009873554805f, alpha = 1.6732632423543772f;
        ys[tid] = z > 0.f ? scale * z : scale * alpha * (expf(z) - 1.f);
    }
    __syncthreads();
    #pragma unroll
    for (int rep = 0; rep < 2; ++rep) {
        int o = tid + rep * 256;
        float s = 0.f;
        #pragma unroll 2
        for (int jj = 0; jj < F_SZ; ++jj) s += ys[jj] * W2[jj * O_SZ + o];
        out[t * O_SZ + o] = s + b2[o];
    }
}

extern "C" void kernel_launch(void* const* d_in, const int* in_sizes, int n_in,
                              void* d_out, int out_size, void* d_ws, size_t ws_size,
                              hipStream_t stream) {
    const float* x    = (const float*)d_in[0];
    const float* h0   = (const float*)d_in[1];
    const float* Wrnn = (const float*)d_in[2];
    const float* brnn = (const float*)d_in[3];
    const float* Wupd = (const float*)d_in[4];
    const float* bupd = (const float*)d_in[5];
    const float* W1   = (const float*)d_in[6];
    const float* b1   = (const float*)d_in[7];
    const float* W2   = (const float*)d_in[8];
    const float* b2   = (const float*)d_in[9];
    float* out = (float*)d_out;

    float* ws = (float*)d_ws;
    float* P      = ws;                              // 48640
    float* h_all  = P + T_SZ * H_SZ;                 // 48640
    float* S      = h_all + T_SZ * H_SZ;             // 48640
    float* zprime = S + T_SZ * H_SZ;                 // 64000
    short* Abf    = (short*)(zprime + T_SZ * F_SZ);  // 262144 shorts

    hipMemsetAsync(zprime, 0, T_SZ * F_SZ * sizeof(float), stream);
    k1_xproj   <<<T_SZ, 256, 0, stream>>>(x, Wrnn, brnn, P);
    k2b_buildAx<<<T_SZ, 256, 0, stream>>>(x, Abf);
    k2_scan    <<<1,    128, 0, stream>>>(Wrnn, h0, P, h_all, S, Abf);
    k3_mfma    <<<743,  512, 0, stream>>>(Wupd, Abf, S, zprime);
    k4_out     <<<T_SZ, 256, 0, stream>>>(x, h_all, W1, bupd, b1, W2, b2, zprime, out);
}

// Round 5
// 730.436 us; speedup vs baseline: 1.5456x; 1.5456x over previous
//
#include <hip/hip_runtime.h>
#include <hip/hip_bf16.h>

#define I_SZ 834
#define H_SZ 190
#define F_SZ 250
#define O_SZ 512
#define T_SZ 256
#define K_SZ 1024   // I+H
#define NW   47500  // F*H: Wupd flat IS W3[1024][47500] row-major

// Abf2 layout: value A[t][k] (bf16 of concat(x_t,h_t)) lives at
//   (k>>3)*2048 + t*8 + (k&7)   -> fragment loads are 256-B coalesced in k3.

typedef __attribute__((ext_vector_type(8))) short short8;
typedef __attribute__((ext_vector_type(4))) float f32x4;

__device__ __forceinline__ short f2bf(float f) {
    union { __hip_bfloat16 h; short s; } u;
    u.h = __float2bfloat16(f);
    return u.s;
}

// -------- K1: P[t][h] = Wrnn[h, H:]·x[t] + brnn[h] --------------------------
__global__ void __launch_bounds__(256) k1_xproj(const float* __restrict__ x,
                                                const float* __restrict__ Wrnn,
                                                const float* __restrict__ brnn,
                                                float* __restrict__ P) {
    __shared__ float xs[I_SZ];
    int t = blockIdx.x;
    for (int i = threadIdx.x; i < I_SZ; i += 256) xs[i] = x[t * I_SZ + i];
    __syncthreads();
    int wave = threadIdx.x >> 6, lane = threadIdx.x & 63;
    for (int h = wave; h < H_SZ; h += 4) {
        const float* wr = Wrnn + h * K_SZ + H_SZ;
        float s = 0.f;
        for (int i = lane; i < I_SZ; i += 64) s += wr[i] * xs[i];
        #pragma unroll
        for (int off = 32; off; off >>= 1) s += __shfl_xor(s, off, 64);
        if (lane == 0) P[t * H_SZ + h] = s + brnn[h];
    }
}

// -------- K2: MFMA scan, 4 waves = 2(n) x 2(k); B[3][6] = 72 VGPR/wave ------
// Wave (wn,wk): n in [wn*96, wn*96+96), k in [wk*96, wk*96+96).
// Cross-k reduction through LDS part[2][192].
__global__ void __launch_bounds__(256, 1) k2_scan(const float* __restrict__ Wrnn,
                                                  const float* __restrict__ h0,
                                                  const float* __restrict__ P,
                                                  float* __restrict__ h_all,
                                                  float* __restrict__ S,
                                                  short* __restrict__ Abf2) {
    __shared__ __align__(16) short hlds[192];
    __shared__ float part[2][192];
    const int tid = threadIdx.x;
    const int w = tid >> 6, l = tid & 63;
    const int wn = w & 1, wk = w >> 1;
    const int l15 = l & 15, lg = l >> 4;
    const short8 zs = {0, 0, 0, 0, 0, 0, 0, 0};

    // one-time: this wave's Whh^T fragments (72 VGPR)
    short8 B[3][6];
    #pragma unroll
    for (int kt = 0; kt < 3; ++kt) {
        #pragma unroll
        for (int nt = 0; nt < 6; ++nt) {
            const int n = wn * 96 + nt * 16 + l15;
            short8 bf = zs;
            #pragma unroll
            for (int e = 0; e < 8; ++e) {
                const int kk = wk * 96 + kt * 32 + lg * 8 + e;
                float v = (n < H_SZ && kk < H_SZ) ? Wrnn[n * K_SZ + kk] : 0.f;
                bf[e] = f2bf(v);
            }
            B[kt][nt] = bf;
        }
    }
    if (tid < 192) hlds[tid] = f2bf((tid < H_SZ) ? h0[tid] : 0.f);
    float Srun = 0.f;
    float pc = (tid < H_SZ) ? P[tid] : 0.f;
    __syncthreads();

    for (int t = 0; t < T_SZ; ++t) {
        short8 a[3];
        #pragma unroll
        for (int kt = 0; kt < 3; ++kt) {
            short8 ar = *reinterpret_cast<const short8*>(&hlds[wk * 96 + kt * 32 + lg * 8]);
            a[kt] = (l15 == 0) ? ar : zs;
        }
        float pn = (t + 1 < T_SZ && tid < H_SZ) ? P[(t + 1) * H_SZ + tid] : 0.f;
        f32x4 acc[6];
        #pragma unroll
        for (int nt = 0; nt < 6; ++nt) {
            f32x4 c = {0.f, 0.f, 0.f, 0.f};
            #pragma unroll
            for (int kt = 0; kt < 3; ++kt)
                c = __builtin_amdgcn_mfma_f32_16x16x32_bf16(a[kt], B[kt][nt], c, 0, 0, 0);
            acc[nt] = c;
        }
        if (l < 16) {
            #pragma unroll
            for (int nt = 0; nt < 6; ++nt)
                part[wk][wn * 96 + nt * 16 + l] = acc[nt][0];   // C row 0 = lanes 0..15, reg 0
        }
        __syncthreads();
        if (tid < H_SZ) {
            float v = tanhf(part[0][tid] + part[1][tid] + pc);
            S[t * H_SZ + tid] = Srun;            // prefix EXCLUDING current step
            h_all[t * H_SZ + tid] = v;
            const int k = I_SZ + tid;
            Abf2[(k >> 3) * (T_SZ * 8) + t * 8 + (k & 7)] = f2bf(v);
            hlds[tid] = f2bf(v);
            Srun += v;
        }
        pc = pn;
        __syncthreads();
    }
}

// -------- K2b: x-part of Abf2 (h-part written by k2) ------------------------
__global__ void __launch_bounds__(256) k2b_buildAx(const float* __restrict__ x,
                                                   short* __restrict__ Abf2) {
    int t = blockIdx.x;
    for (int i = threadIdx.x; i < I_SZ; i += 256)
        Abf2[(i >> 3) * (T_SZ * 8) + t * 8 + (i & 7)] = f2bf(x[t * I_SZ + i]);
}

// -------- K3: transposed MFMA GEMM C^T[n][t] = W3^T @ A^T, fused S-contract -
// Block: 64 n-rows, all 256 t. 8 waves = 4(n-tile) x 2(t-half).
// bfr loads now 256-B coalesced via Abf2 layout.
__global__ void __launch_bounds__(512, 1) k3_mfma(const float* __restrict__ Wupd,
                                                  const short* __restrict__ Abf2,
                                                  const float* __restrict__ S,
                                                  float* __restrict__ zprime) {
    __shared__ __align__(16) float Bs[2][32][66];   // fp32 W-slab [k=32][n=64 pad 66]
    const int tid = threadIdx.x;
    const int bn0 = blockIdx.x * 64;
    const int l = tid & 63, wv = tid >> 6;
    const int wn = wv & 3;              // n-tile 0..3
    const int wt = wv >> 2;             // t-half 0..1
    const int l15 = l & 15, lg = l >> 4;

    const int sr = tid >> 4;
    const int sc = (tid & 15) * 4;
    const bool sval = (bn0 + sc + 4) <= NW;     // NW % 4 == 0
    const float* wsrc = Wupd + (size_t)sr * NW + bn0 + sc;

    float4 f = sval ? *reinterpret_cast<const float4*>(wsrc)
                    : make_float4(0.f, 0.f, 0.f, 0.f);

    f32x4 acc[8];
    #pragma unroll
    for (int tt = 0; tt < 8; ++tt) acc[tt] = (f32x4){0.f, 0.f, 0.f, 0.f};

    *reinterpret_cast<float2*>(&Bs[0][sr][sc])     = make_float2(f.x, f.y);
    *reinterpret_cast<float2*>(&Bs[0][sr][sc + 2]) = make_float2(f.z, f.w);
    __syncthreads();

    for (int ks = 0; ks < 32; ++ks) {
        const int cur = ks & 1;
        if (ks < 31) {
            const float* nsrc = wsrc + (size_t)(ks + 1) * 32 * NW;
            f = sval ? *reinterpret_cast<const float4*>(nsrc)
                     : make_float4(0.f, 0.f, 0.f, 0.f);
        }
        // B-operand: coalesced 256-B slab reads from Abf2
        short8 bfr[8];
        #pragma unroll
        for (int tt = 0; tt < 8; ++tt) {
            const short* ap = Abf2 + (size_t)(ks * 4 + lg) * (T_SZ * 8)
                                   + (size_t)(wt * 128 + tt * 16 + l15) * 8;
            bfr[tt] = *reinterpret_cast<const short8*>(ap);
        }
        // A-operand: W3^T, row = n (lane l15), k = lg*8+e  (fp32 LDS -> bf16)
        short8 afr;
        #pragma unroll
        for (int e = 0; e < 8; ++e)
            afr[e] = f2bf(Bs[cur][lg * 8 + e][wn * 16 + l15]);
        #pragma unroll
        for (int tt = 0; tt < 8; ++tt)
            acc[tt] = __builtin_amdgcn_mfma_f32_16x16x32_bf16(afr, bfr[tt], acc[tt], 0, 0, 0);

        if (ks < 31) {
            *reinterpret_cast<float2*>(&Bs[cur ^ 1][sr][sc])     = make_float2(f.x, f.y);
            *reinterpret_cast<float2*>(&Bs[cur ^ 1][sr][sc + 2]) = make_float2(f.z, f.w);
            __syncthreads();
        }
    }

    // epilogue: z'[t][j] += sum_h C^T[n][t] * S[t][h(n)], bucketed by j
    const int jlo = bn0 / H_SZ;
    float pj[8][2];
    #pragma unroll
    for (int tt = 0; tt < 8; ++tt) { pj[tt][0] = 0.f; pj[tt][1] = 0.f; }
    #pragma unroll
    for (int r = 0; r < 4; ++r) {
        const int n = bn0 + wn * 16 + lg * 4 + r;
        const bool ok = n < NW;
        const int nc = ok ? n : NW - 1;
        const int j = nc / H_SZ;
        const int h = nc - j * H_SZ;
        const bool b0 = (j == jlo);
        #pragma unroll
        for (int tt = 0; tt < 8; ++tt) {
            const int t = wt * 128 + tt * 16 + l15;
            const float sv = S[t * H_SZ + h];
            const float prod = ok ? acc[tt][r] * sv : 0.f;
            pj[tt][0] += b0 ? prod : 0.f;
            pj[tt][1] += b0 ? 0.f : prod;
        }
    }
    #pragma unroll
    for (int tt = 0; tt < 8; ++tt) {
        #pragma unroll
        for (int b = 0; b < 2; ++b) {
            float v = pj[tt][b];
            v += __shfl_xor(v, 16, 64);
            v += __shfl_xor(v, 32, 64);
            if (lg == 0) {
                const int j = jlo + b;
                if (j < F_SZ) {
                    const int t = wt * 128 + tt * 16 + l15;
                    atomicAdd(&zprime[t * F_SZ + j], v);
                }
            }
        }
    }
}

// -------- K4: z -> selu -> @W2 + b2 -----------------------------------------
__global__ void __launch_bounds__(256) k4_out(const float* __restrict__ x,
                                              const float* __restrict__ h_all,
                                              const float* __restrict__ W1,
                                              const float* __restrict__ bupd,
                                              const float* __restrict__ b1,
                                              const float* __restrict__ W2,
                                              const float* __restrict__ b2,
                                              const float* __restrict__ zprime,
                                              float* __restrict__ out) {
    __shared__ float as[K_SZ];
    __shared__ float ys[256];
    int t = blockIdx.x;
    int tid = threadIdx.x;
    for (int i = tid; i < K_SZ; i += 256)
        as[i] = (i < I_SZ) ? x[t * I_SZ + i] : h_all[t * H_SZ + (i - I_SZ)];
    __syncthreads();
    if (tid < F_SZ) {
        float d1 = 0.f, d2 = 0.f;
        #pragma unroll 4
        for (int i = 0; i < K_SZ; ++i) {
            float av = as[i];
            d1 += av * W1[i * F_SZ + tid];
            d2 += av * bupd[i * F_SZ + tid];
        }
        float z = zprime[t * F_SZ + tid] + d1 + (float)t * d2 + b1[tid];
        const float scale = 1.0507009873554805f, alpha = 1.6732632423543772f;
        ys[tid] = z > 0.f ? scale * z : scale * alpha * (expf(z) - 1.f);
    }
    __syncthreads();
    #pragma unroll
    for (int rep = 0; rep < 2; ++rep) {
        int o = tid + rep * 256;
        float s = 0.f;
        #pragma unroll 2
        for (int jj = 0; jj < F_SZ; ++jj) s += ys[jj] * W2[jj * O_SZ + o];
        out[t * O_SZ + o] = s + b2[o];
    }
}

extern "C" void kernel_launch(void* const* d_in, const int* in_sizes, int n_in,
                              void* d_out, int out_size, void* d_ws, size_t ws_size,
                              hipStream_t stream) {
    const float* x    = (const float*)d_in[0];
    const float* h0   = (const float*)d_in[1];
    const float* Wrnn = (const float*)d_in[2];
    const float* brnn = (const float*)d_in[3];
    const float* Wupd = (const float*)d_in[4];
    const float* bupd = (const float*)d_in[5];
    const float* W1   = (const float*)d_in[6];
    const float* b1   = (const float*)d_in[7];
    const float* W2   = (const float*)d_in[8];
    const float* b2   = (const float*)d_in[9];
    float* out = (float*)d_out;

    float* ws = (float*)d_ws;
    float* P      = ws;                              // 48640
    float* h_all  = P + T_SZ * H_SZ;                 // 48640
    float* S      = h_all + T_SZ * H_SZ;             // 48640
    float* zprime = S + T_SZ * H_SZ;                 // 64000
    short* Abf2   = (short*)(zprime + T_SZ * F_SZ);  // 262144 shorts

    hipMemsetAsync(zprime, 0, T_SZ * F_SZ * sizeof(float), stream);
    k1_xproj   <<<T_SZ, 256, 0, stream>>>(x, Wrnn, brnn, P);
    k2b_buildAx<<<T_SZ, 256, 0, stream>>>(x, Abf2);
    k2_scan    <<<1,    256, 0, stream>>>(Wrnn, h0, P, h_all, S, Abf2);
    k3_mfma    <<<743,  512, 0, stream>>>(Wupd, Abf2, S, zprime);
    k4_out     <<<T_SZ, 256, 0, stream>>>(x, h_all, W1, bupd, b1, W2, b2, zprime, out);
}

// Round 6
// 630.891 us; speedup vs baseline: 1.7895x; 1.1578x over previous
//
#include <hip/hip_runtime.h>
#include <hip/hip_bf16.h>

#define I_SZ 834
#define H_SZ 190
#define F_SZ 250
#define O_SZ 512
#define T_SZ 256
#define K_SZ 1024   // I+H
#define NW   47500  // F*H: Wupd flat IS W3[1024][47500] row-major

// Abf2 layout: value A[t][k] (bf16 of concat(x_t,h_t)) lives at
//   (k>>3)*2048 + t*8 + (k&7)   -> b128 fragment loads are 256-B coalesced.

typedef __attribute__((ext_vector_type(8))) short short8;
typedef __attribute__((ext_vector_type(4))) float f32x4;

__device__ __forceinline__ short f2bf(float f) {
    union { __hip_bfloat16 h; short s; } u;
    u.h = __float2bfloat16(f);
    return u.s;
}

// -------- K2b: x-part of Abf2 + zero pad k in [834,864) ---------------------
__global__ void __launch_bounds__(256) k2b_buildAx(const float* __restrict__ x,
                                                   short* __restrict__ Abf2) {
    int t = blockIdx.x;
    for (int i = threadIdx.x; i < I_SZ; i += 256)
        Abf2[(i >> 3) * (T_SZ * 8) + t * 8 + (i & 7)] = f2bf(x[t * I_SZ + i]);
    for (int i = I_SZ + threadIdx.x; i < 864; i += 256)
        Abf2[(i >> 3) * (T_SZ * 8) + t * 8 + (i & 7)] = 0;
}

// -------- K1: P^T[h][t] = Wx^T @ x^T via MFMA (12 blocks x 4 waves) ---------
// Block bh: h-rows [bh*16, bh*16+16). Wave w: t-cols [w*64, w*64+64).
__global__ void __launch_bounds__(256) k1_mfma(const short* __restrict__ Abf2,
                                               const float* __restrict__ Wrnn,
                                               const float* __restrict__ brnn,
                                               float* __restrict__ P) {
    const int tid = threadIdx.x;
    const int bh = blockIdx.x;
    const int w = tid >> 6, l = tid & 63;
    const int l15 = l & 15, lg = l >> 4;
    const int h = bh * 16 + l15;            // A-operand row
    const int hc = (h < H_SZ) ? h : H_SZ - 1;

    f32x4 acc[4];
    #pragma unroll
    for (int tt = 0; tt < 4; ++tt) acc[tt] = (f32x4){0.f, 0.f, 0.f, 0.f};

    for (int ks = 0; ks < 27; ++ks) {       // K = 864 (zero-padded past 834)
        short8 afr;
        #pragma unroll
        for (int e = 0; e < 8; ++e) {
            const int kk = ks * 32 + lg * 8 + e;
            float v = (kk < I_SZ && h < H_SZ) ? Wrnn[hc * K_SZ + H_SZ + kk] : 0.f;
            afr[e] = f2bf(v);
        }
        #pragma unroll
        for (int tt = 0; tt < 4; ++tt) {
            const short* ap = Abf2 + (size_t)(ks * 4 + lg) * (T_SZ * 8)
                                   + (size_t)(w * 64 + tt * 16 + l15) * 8;
            short8 bfr = *reinterpret_cast<const short8*>(ap);
            acc[tt] = __builtin_amdgcn_mfma_f32_16x16x32_bf16(afr, bfr, acc[tt], 0, 0, 0);
        }
    }
    #pragma unroll
    for (int tt = 0; tt < 4; ++tt) {
        const int t = w * 64 + tt * 16 + l15;
        #pragma unroll
        for (int r = 0; r < 4; ++r) {
            const int hrow = bh * 16 + lg * 4 + r;
            if (hrow < H_SZ) P[t * H_SZ + hrow] = acc[tt][r] + brnn[hrow];
        }
    }
}

// -------- K2: MFMA scan, 4 waves = 2(n) x 2(k); B[3][6] = 72 VGPR/wave ------
__global__ void __launch_bounds__(256, 1) k2_scan(const float* __restrict__ Wrnn,
                                                  const float* __restrict__ h0,
                                                  const float* __restrict__ P,
                                                  float* __restrict__ h_all,
                                                  float* __restrict__ S,
                                                  short* __restrict__ Abf2) {
    __shared__ __align__(16) short hlds[192];
    __shared__ float part[2][192];
    const int tid = threadIdx.x;
    const int w = tid >> 6, l = tid & 63;
    const int wn = w & 1, wk = w >> 1;
    const int l15 = l & 15, lg = l >> 4;
    const short8 zs = {0, 0, 0, 0, 0, 0, 0, 0};

    short8 B[3][6];
    #pragma unroll
    for (int kt = 0; kt < 3; ++kt) {
        #pragma unroll
        for (int nt = 0; nt < 6; ++nt) {
            const int n = wn * 96 + nt * 16 + l15;
            short8 bf = zs;
            #pragma unroll
            for (int e = 0; e < 8; ++e) {
                const int kk = wk * 96 + kt * 32 + lg * 8 + e;
                float v = (n < H_SZ && kk < H_SZ) ? Wrnn[n * K_SZ + kk] : 0.f;
                bf[e] = f2bf(v);
            }
            B[kt][nt] = bf;
        }
    }
    if (tid < 192) hlds[tid] = f2bf((tid < H_SZ) ? h0[tid] : 0.f);
    float Srun = 0.f;
    float pc = (tid < H_SZ) ? P[tid] : 0.f;
    __syncthreads();

    for (int t = 0; t < T_SZ; ++t) {
        short8 a[3];
        #pragma unroll
        for (int kt = 0; kt < 3; ++kt) {
            short8 ar = *reinterpret_cast<const short8*>(&hlds[wk * 96 + kt * 32 + lg * 8]);
            a[kt] = (l15 == 0) ? ar : zs;
        }
        float pn = (t + 1 < T_SZ && tid < H_SZ) ? P[(t + 1) * H_SZ + tid] : 0.f;
        f32x4 acc[6];
        #pragma unroll
        for (int nt = 0; nt < 6; ++nt) {
            f32x4 c = {0.f, 0.f, 0.f, 0.f};
            #pragma unroll
            for (int kt = 0; kt < 3; ++kt)
                c = __builtin_amdgcn_mfma_f32_16x16x32_bf16(a[kt], B[kt][nt], c, 0, 0, 0);
            acc[nt] = c;
        }
        if (l < 16) {
            #pragma unroll
            for (int nt = 0; nt < 6; ++nt)
                part[wk][wn * 96 + nt * 16 + l] = acc[nt][0];
        }
        __syncthreads();
        if (tid < H_SZ) {
            float v = tanhf(part[0][tid] + part[1][tid] + pc);
            S[t * H_SZ + tid] = Srun;            // prefix EXCLUDING current step
            h_all[t * H_SZ + tid] = v;
            const int k = I_SZ + tid;
            Abf2[(k >> 3) * (T_SZ * 8) + t * 8 + (k & 7)] = f2bf(v);
            hlds[tid] = f2bf(v);
            Srun += v;
        }
        pc = pn;
        __syncthreads();
    }
}

// -------- K3 v3: barrier-free MFMA GEMM, operands direct from global --------
// Block: 64 n-rows, 256 t. 8 waves = 4(wn) x 2(wt). No LDS tiles, no syncs.
__global__ void __launch_bounds__(512) k3_mfma(const float* __restrict__ Wupd,
                                               const short* __restrict__ Abf2,
                                               const float* __restrict__ S,
                                               float* __restrict__ zprime) {
    const int tid = threadIdx.x;
    const int bn0 = blockIdx.x * 64;
    const int l = tid & 63, wv = tid >> 6;
    const int wn = wv & 3;              // n-tile 0..3
    const int wt = wv >> 2;             // t-half 0..1
    const int l15 = l & 15, lg = l >> 4;

    const int ncol = bn0 + wn * 16 + l15;
    const bool nok = ncol < NW;
    const int ncl = nok ? ncol : NW - 1;

    f32x4 acc[8];
    #pragma unroll
    for (int tt = 0; tt < 8; ++tt) acc[tt] = (f32x4){0.f, 0.f, 0.f, 0.f};

    for (int ks = 0; ks < 32; ++ks) {
        short8 afr;
        #pragma unroll
        for (int e = 0; e < 8; ++e) {
            const size_t kk = (size_t)ks * 32 + lg * 8 + e;
            const float v = Wupd[kk * NW + ncl];
            afr[e] = nok ? f2bf(v) : (short)0;
        }
        #pragma unroll
        for (int tt = 0; tt < 8; ++tt) {
            const short* ap = Abf2 + (size_t)(ks * 4 + lg) * (T_SZ * 8)
                                   + (size_t)(wt * 128 + tt * 16 + l15) * 8;
            short8 bfr = *reinterpret_cast<const short8*>(ap);
            acc[tt] = __builtin_amdgcn_mfma_f32_16x16x32_bf16(afr, bfr, acc[tt], 0, 0, 0);
        }
    }

    // epilogue: z'[t][j] += sum_h C^T[n][t] * S[t][h(n)], bucketed by j
    const int jlo = bn0 / H_SZ;
    float pj[8][2];
    #pragma unroll
    for (int tt = 0; tt < 8; ++tt) { pj[tt][0] = 0.f; pj[tt][1] = 0.f; }
    #pragma unroll
    for (int r = 0; r < 4; ++r) {
        const int n = bn0 + wn * 16 + lg * 4 + r;
        const bool ok = n < NW;
        const int nc = ok ? n : NW - 1;
        const int j = nc / H_SZ;
        const int h = nc - j * H_SZ;
        const bool b0 = (j == jlo);
        #pragma unroll
        for (int tt = 0; tt < 8; ++tt) {
            const int t = wt * 128 + tt * 16 + l15;
            const float sv = S[t * H_SZ + h];
            const float prod = ok ? acc[tt][r] * sv : 0.f;
            pj[tt][0] += b0 ? prod : 0.f;
            pj[tt][1] += b0 ? 0.f : prod;
        }
    }
    #pragma unroll
    for (int tt = 0; tt < 8; ++tt) {
        #pragma unroll
        for (int b = 0; b < 2; ++b) {
            float v = pj[tt][b];
            v += __shfl_xor(v, 16, 64);
            v += __shfl_xor(v, 32, 64);
            if (lg == 0) {
                const int j = jlo + b;
                if (j < F_SZ) {
                    const int t = wt * 128 + tt * 16 + l15;
                    atomicAdd(&zprime[t * F_SZ + j], v);
                }
            }
        }
    }
}

// -------- K4: z -> selu -> @W2 + b2 -----------------------------------------
__global__ void __launch_bounds__(256) k4_out(const float* __restrict__ x,
                                              const float* __restrict__ h_all,
                                              const float* __restrict__ W1,
                                              const float* __restrict__ bupd,
                                              const float* __restrict__ b1,
                                              const float* __restrict__ W2,
                                              const float* __restrict__ b2,
                                              const float* __restrict__ zprime,
                                              float* __restrict__ out) {
    __shared__ float as[K_SZ];
    __shared__ float ys[256];
    int t = blockIdx.x;
    int tid = threadIdx.x;
    for (int i = tid; i < K_SZ; i += 256)
        as[i] = (i < I_SZ) ? x[t * I_SZ + i] : h_all[t * H_SZ + (i - I_SZ)];
    __syncthreads();
    if (tid < F_SZ) {
        float d1 = 0.f, d2 = 0.f;
        #pragma unroll 4
        for (int i = 0; i < K_SZ; ++i) {
            float av = as[i];
            d1 += av * W1[i * F_SZ + tid];
            d2 += av * bupd[i * F_SZ + tid];
        }
        float z = zprime[t * F_SZ + tid] + d1 + (float)t * d2 + b1[tid];
        const float scale = 1.0507009873554805f, alpha = 1.6732632423543772f;
        ys[tid] = z > 0.f ? scale * z : scale * alpha * (expf(z) - 1.f);
    }
    __syncthreads();
    #pragma unroll
    for (int rep = 0; rep < 2; ++rep) {
        int o = tid + rep * 256;
        float s = 0.f;
        #pragma unroll 2
        for (int jj = 0; jj < F_SZ; ++jj) s += ys[jj] * W2[jj * O_SZ + o];
        out[t * O_SZ + o] = s + b2[o];
    }
}

extern "C" void kernel_launch(void* const* d_in, const int* in_sizes, int n_in,
                              void* d_out, int out_size, void* d_ws, size_t ws_size,
                              hipStream_t stream) {
    const float* x    = (const float*)d_in[0];
    const float* h0   = (const float*)d_in[1];
    const float* Wrnn = (const float*)d_in[2];
    const float* brnn = (const float*)d_in[3];
    const float* Wupd = (const float*)d_in[4];
    const float* bupd = (const float*)d_in[5];
    const float* W1   = (const float*)d_in[6];
    const float* b1   = (const float*)d_in[7];
    const float* W2   = (const float*)d_in[8];
    const float* b2   = (const float*)d_in[9];
    float* out = (float*)d_out;

    float* ws = (float*)d_ws;
    float* P      = ws;                              // 48640
    float* h_all  = P + T_SZ * H_SZ;                 // 48640
    float* S      = h_all + T_SZ * H_SZ;             // 48640
    float* zprime = S + T_SZ * H_SZ;                 // 64000
    short* Abf2   = (short*)(zprime + T_SZ * F_SZ);  // 262144 shorts

    hipMemsetAsync(zprime, 0, T_SZ * F_SZ * sizeof(float), stream);
    k2b_buildAx<<<T_SZ, 256, 0, stream>>>(x, Abf2);
    k1_mfma    <<<12,   256, 0, stream>>>(Abf2, Wrnn, brnn, P);
    k2_scan    <<<1,    256, 0, stream>>>(Wrnn, h0, P, h_all, S, Abf2);
    k3_mfma    <<<743,  512, 0, stream>>>(Wupd, Abf2, S, zprime);
    k4_out     <<<T_SZ, 256, 0, stream>>>(x, h_all, W1, bupd, b1, W2, b2, zprime, out);
}